// Round 5
// baseline (362.708 us; speedup 1.0000x reference)
//
#include <hip/hip_runtime.h>

typedef unsigned short u16;
typedef unsigned int   u32;
typedef __attribute__((ext_vector_type(8))) short short8;
typedef __attribute__((ext_vector_type(4))) float f32x4;

__device__ __forceinline__ float bf2f(u16 v) {
  return __uint_as_float(((u32)v) << 16);
}
__device__ __forceinline__ u16 f2bf(float f) {
  u32 u = __float_as_uint(f);
  u32 r = (u + 0x7FFFu + ((u >> 16) & 1u)) >> 16;   // RNE
  return (u16)r;
}
// NaN-propagating ReLU (fmaxf(NaN,0)=0 would hide poison as zeros)
__device__ __forceinline__ float relu(float x) { return x < 0.f ? 0.f : x; }

// async global->LDS, 16B/lane; LDS dest = wave-uniform base + lane*16
__device__ __forceinline__ void gld16(const void* g, void* l) {
  __builtin_amdgcn_global_load_lds((const __attribute__((address_space(1))) u32*)g,
                                   (__attribute__((address_space(3))) u32*)l, 16, 0, 0);
}

// ---------------------------------------------------------------------------
// 1a. partial column sums of frame batch 0: chunk ch sums c in [ch*64,ch*64+64)
__global__ void colmean_part_kernel(const float* __restrict__ frame,
                                    double* __restrict__ partD) {
  int tf = blockIdx.x * 256 + threadIdx.x;           // 4096
  int ch = blockIdx.y;                               // 8 chunks
  const float* f0 = frame + tf + (size_t)ch * 64 * 4096;
  double s = 0.0;
  for (int c = 0; c < 64; ++c) s += (double)f0[(size_t)c * 4096];
  partD[ch * 4096 + tf] = s;
}

// ---------------------------------------------------------------------------
// 2. f64: mean = (in-order chunk combine)/512; S = sum; q = mean/S; cumsum;
//    cdf = min(int(c*2048), 2047).
__global__ void scanD_kernel(const double* __restrict__ partD, int* __restrict__ cdf) {
  __shared__ double part[256];
  __shared__ double base[256];
  __shared__ double Ss;
  int tid = threadIdx.x;
  double loc[16];
  double s = 0.0;
#pragma unroll
  for (int i = 0; i < 16; ++i) {
    int tf = tid * 16 + i;
    double m = 0.0;
#pragma unroll
    for (int ch = 0; ch < 8; ++ch) m += partD[ch * 4096 + tf];  // in c-order
    loc[i] = m / 512.0;
    s += loc[i];
  }
  part[tid] = s;
  __syncthreads();
  if (tid == 0) {
    double t = 0.0;
    for (int i = 0; i < 256; ++i) t += part[i];
    Ss = t;
  }
  __syncthreads();
  double S = Ss;
  s = 0.0;
#pragma unroll
  for (int i = 0; i < 16; ++i) { loc[i] = loc[i] / S; s += loc[i]; }
  part[tid] = s;
  __syncthreads();
  if (tid == 0) {
    double c = 0.0;
    for (int i = 0; i < 256; ++i) { base[i] = c; c += part[i]; }
  }
  __syncthreads();
  double c = base[tid];
#pragma unroll
  for (int i = 0; i < 16; ++i) {
    c += loc[i];
    int iv = (int)(c * 2048.0);                      // trunc = astype(int32)
    cdf[tid * 16 + i] = iv < 2047 ? iv : 2047;
  }
}

// ---------------------------------------------------------------------------
// 3. idx[target] = first argmin_j |cdf[j]-target|
__global__ void argmin_kernel(const int* __restrict__ cdf, int* __restrict__ idx) {
  __shared__ int sd[256], sj[256];
  int target = blockIdx.x;                            // 2048 blocks
  int tid = threadIdx.x;
  int best = 0x7fffffff, bj = 0x7fffffff;
  for (int j = tid; j < 4096; j += 256) {
    int d = cdf[j] - target; d = d < 0 ? -d : d;
    if (d < best) { best = d; bj = j; }               // strict < keeps first
  }
  sd[tid] = best; sj[tid] = bj;
  __syncthreads();
  for (int s = 128; s > 0; s >>= 1) {
    if (tid < s) {
      if (sd[tid+s] < sd[tid] || (sd[tid+s] == sd[tid] && sj[tid+s] < sj[tid])) {
        sd[tid] = sd[tid+s]; sj[tid] = sj[tid+s];
      }
    }
    __syncthreads();
  }
  if (tid == 0) idx[target] = sj[0];
}

// ---------------------------------------------------------------------------
// 4. gather transposed: X3T[b][t][c] = bf16(frame[b][c][idx[t]]), c in [0,512)
__global__ void gatherT_kernel(const float* __restrict__ frame, const int* __restrict__ idx,
                               u16* __restrict__ X3T) {
  __shared__ u16 tile[64][65];
  __shared__ int sidx[64];
  int cb = blockIdx.x * 64, t0 = blockIdx.y * 64, b = blockIdx.z;
  int tid = threadIdx.x;
  if (tid < 64) {
    int it = idx[t0 + tid];
    sidx[tid] = it < 0 ? 0 : (it > 4095 ? 4095 : it);
  }
  __syncthreads();
  const float* fb = frame + (size_t)b * 512 * 4096;
  for (int i = tid; i < 4096; i += 256) {
    int r = i >> 6, tt = i & 63;        // r = c-local, tt = t-local
    tile[tt][r] = f2bf(fb[(size_t)(cb + r) * 4096 + sidx[tt]]);
  }
  __syncthreads();
  u16* xb = X3T + (size_t)b * 2048 * 2048;
  for (int i = tid; i < 4096; i += 256) {
    int r = i >> 6, cc = i & 63;        // r = t-local, cc = c-local
    xb[(size_t)(t0 + r) * 2048 + cb + cc] = tile[r][cc];
  }
}

// ---------------------------------------------------------------------------
// 5. feature (B,512c,2048t) fp32 -> featT (B,2048t,512c) bf16, LDS 64x64
__global__ void transposeCT_kernel(const float* __restrict__ X, u16* __restrict__ XT) {
  __shared__ u16 tile[64][65];
  int cb = blockIdx.x * 64, t0 = blockIdx.y * 64, b = blockIdx.z;
  int tid = threadIdx.x;
  const float* xb = X + (size_t)b * 512 * 2048;
  for (int i = tid; i < 4096; i += 256) {
    int r = i >> 6, tt = i & 63;        // coalesced along t
    tile[tt][r] = f2bf(xb[(size_t)(cb + r) * 2048 + t0 + tt]);
  }
  __syncthreads();
  u16* xtb = XT + (size_t)b * 2048 * 512;
  for (int i = tid; i < 4096; i += 256) {
    int r = i >> 6, cc = i & 63;
    xtb[(size_t)(t0 + r) * 512 + cb + cc] = tile[r][cc];
  }
}

// ---------------------------------------------------------------------------
// 6. W1 (262144) ++ W2 (524288) fp32 -> W12b bf16 (stacked rows, K=512)
__global__ void convW12_kernel(const float* __restrict__ W1, const float* __restrict__ W2,
                               u16* __restrict__ dst) {
  int i = blockIdx.x * 256 + threadIdx.x;            // 786432
  dst[i] = f2bf(i < 262144 ? W1[i] : W2[i - 262144]);
}
__global__ void convW_kernel(const float* __restrict__ src, u16* __restrict__ dst, int n) {
  int i = blockIdx.x * 256 + threadIdx.x;
  if (i < n) dst[i] = f2bf(src[i]);
}

// ---------------------------------------------------------------------------
// 7a. fused GEMM1+2 (r2-verified): Y12 + bias; GN1/GN2 stage-1 stats fused.
//     M=1536, N=2048, K=512. 64x128 tile, 2 waves. Conflict-free both-sides
//     16B-slot XOR swizzle (slot ^= (row>>1)&3).
__global__ __launch_bounds__(128) void gemm12_kernel(
    const u16* __restrict__ A, const u16* __restrict__ Bt,
    const float* __restrict__ b1, const float* __restrict__ b2,
    float* __restrict__ Y, float* __restrict__ raw1, float* __restrict__ raw2)
{
  const int K = 512;
  __shared__ short As[2][2048];   // [buf][64 m][32 k]
  __shared__ short Bs[2][4096];   // [buf][128 n][32 k]
  const int tid = threadIdx.x;
  const int lane = tid & 63;
  const int w = tid >> 6;
  const int nt = blockIdx.x, mt = blockIdx.y, bb = blockIdx.z;
  const u16* Ab = A + (size_t)mt * 64 * K;
  const u16* Bb = Bt + ((size_t)bb * 2048 + (size_t)nt * 128) * K;
  const int lm = lane & 15, lq = lane >> 4;
  f32x4 acc[4][4] = {};

  auto stage = [&](int buf, int kt) {
#pragma unroll
    for (int p = 0; p < 2; ++p) {
      int chunk = tid + 128 * p;
      int row = chunk >> 2;
      int ko = ((chunk & 3) ^ ((row >> 1) & 3)) << 3;   // source pre-swizzle
      gld16(Ab + (size_t)row * K + kt + ko, (char*)As[buf] + chunk * 16);
    }
#pragma unroll
    for (int p = 0; p < 4; ++p) {
      int chunk = tid + 128 * p;
      int row = chunk >> 2;
      int ko = ((chunk & 3) ^ ((row >> 1) & 3)) << 3;
      gld16(Bb + (size_t)row * K + kt + ko, (char*)Bs[buf] + chunk * 16);
    }
  };

  stage(0, 0);
  for (int s = 0; s < 16; ++s) {
    int cur = s & 1;
    __syncthreads();
    if (s + 1 < 16) stage(cur ^ 1, (s + 1) << 5);
    short8 af[4], bfv[4];
#pragma unroll
    for (int i = 0; i < 4; ++i) {
      int r = i * 16 + lm;
      af[i] = *(const short8*)(As[cur] + r * 32 + ((lq ^ ((r >> 1) & 3)) << 3));
    }
#pragma unroll
    for (int j = 0; j < 4; ++j) {
      int r = w * 64 + j * 16 + lm;
      bfv[j] = *(const short8*)(Bs[cur] + r * 32 + ((lq ^ ((r >> 1) & 3)) << 3));
    }
#pragma unroll
    for (int i = 0; i < 4; ++i)
#pragma unroll
      for (int j = 0; j < 4; ++j)
        acc[i][j] = __builtin_amdgcn_mfma_f32_16x16x32_bf16(af[i], bfv[j], acc[i][j], 0, 0, 0);
  }

  float s1[4] = {0.f, 0.f, 0.f, 0.f};
  float s2[4] = {0.f, 0.f, 0.f, 0.f};
#pragma unroll
  for (int i = 0; i < 4; ++i) {
    int mbase = mt * 64 + i * 16 + lq * 4;
#pragma unroll
    for (int e = 0; e < 4; ++e) {
      int m = mbase + e;
      float bv = m < 512 ? b1[m] : b2[m - 512];
      float* yp = Y + ((size_t)bb * 1536 + m) * 2048 + nt * 128 + w * 64 + lm;
#pragma unroll
      for (int j = 0; j < 4; ++j) {
        float v = acc[i][j][e] + bv;
        yp[j * 16] = v;
        s1[i] += v; s2[i] += v * v;
      }
    }
  }
#pragma unroll
  for (int i = 0; i < 4; ++i) {
#pragma unroll
    for (int off = 32; off > 0; off >>= 1) {
      s1[i] += __shfl_xor(s1[i], off);
      s2[i] += __shfl_xor(s2[i], off);
    }
  }
  if (lane == 0) {
    if (mt < 8) {                                  // GN1: cpg=16, frag = 1 group
#pragma unroll
      for (int i = 0; i < 4; ++i) {
        int g = mt * 4 + i;
        atomicAdd(&raw1[(bb * 32 + g) * 2],     s1[i]);
        atomicAdd(&raw1[(bb * 32 + g) * 2 + 1], s2[i]);
      }
    } else {                                       // GN2: cpg=32, 2 frags = 1 group
#pragma unroll
      for (int i = 0; i < 2; ++i) {
        int g = (mt - 8) * 2 + i;
        atomicAdd(&raw2[(bb * 32 + g) * 2],     s1[2 * i] + s1[2 * i + 1]);
        atomicAdd(&raw2[(bb * 32 + g) * 2 + 1], s2[2 * i] + s2[2 * i + 1]);
      }
    }
  }
}

// ---------------------------------------------------------------------------
// 7b. fused GEMM3 + GN3 + ReLU in ONE kernel via SOFTWARE grid barrier.
//     Full-K, BK=64 (32 K-steps). M=512, N=2048, K=2048.
//     grid (16,8,4) = 512 blocks @ 48KiB LDS: capacity = 3/CU (163840/49152),
//     grid needs only 2/CU -> all blocks co-resident by construction, so the
//     arrive-and-spin barrier cannot deadlock. Stats via device-scope atomics;
//     release RMW on arrival + acquire loads after -> cross-XCD visible.
//     Replaces gemm3s + stats3p + statsFin + norm3 (saves ~100MB HBM traffic).
__global__ __launch_bounds__(128) void gemm3f_kernel(
    const u16* __restrict__ A, const u16* __restrict__ Bt,
    const float* __restrict__ bias,
    const float* __restrict__ g3, const float* __restrict__ be3,
    float* __restrict__ raw3, int* __restrict__ bar,
    float* __restrict__ out)
{
  const int K = 2048;
  __shared__ char smem[49152];          // As[2][64][64] 16KB | Bs[2][128][64] 32KB
  short* As0 = (short*)smem;            // As[buf] = As0 + buf*4096
  short* Bs0 = (short*)(smem + 16384);  // Bs[buf] = Bs0 + buf*8192
  const int tid = threadIdx.x;
  const int lane = tid & 63;
  const int w = tid >> 6;
  const int nt = blockIdx.x, mt = blockIdx.y, bb = blockIdx.z;
  const u16* Ab = A + (size_t)mt * 64 * K;
  const u16* Bb = Bt + ((size_t)bb * 2048 + (size_t)nt * 128) * K;
  const int lm = lane & 15, lq = lane >> 4;
  f32x4 acc[4][4] = {};

  // rows are 128B = 8x16B slots; LDS linear, source slot pre-swizzled by
  // seg ^ (row&7); ds_read applies the same XOR -> 2-way max (free).
  auto stage = [&](int buf, int kt) {
#pragma unroll
    for (int p = 0; p < 4; ++p) {
      int chunk = tid + 128 * p;                 // 512 chunks: 64 rows x 8
      int row = chunk >> 3, seg = chunk & 7;
      gld16(Ab + (size_t)row * K + kt + ((seg ^ (row & 7)) << 3),
            (char*)(As0 + buf * 4096) + chunk * 16);
    }
#pragma unroll
    for (int p = 0; p < 8; ++p) {
      int chunk = tid + 128 * p;                 // 1024 chunks: 128 rows x 8
      int row = chunk >> 3, seg = chunk & 7;
      gld16(Bb + (size_t)row * K + kt + ((seg ^ (row & 7)) << 3),
            (char*)(Bs0 + buf * 8192) + chunk * 16);
    }
  };

  stage(0, 0);
  for (int s = 0; s < 32; ++s) {
    int cur = s & 1;
    __syncthreads();
    if (s + 1 < 32) stage(cur ^ 1, (s + 1) << 6);
    const short* Asc = As0 + cur * 4096;
    const short* Bsc = Bs0 + cur * 8192;
#pragma unroll
    for (int kk = 0; kk < 2; ++kk) {
      short8 af[4], bfv[4];
#pragma unroll
      for (int i = 0; i < 4; ++i) {
        int r = i * 16 + lm;
        af[i] = *(const short8*)(Asc + r * 64 + (((kk * 4 + lq) ^ (r & 7)) << 3));
      }
#pragma unroll
      for (int j = 0; j < 4; ++j) {
        int r = w * 64 + j * 16 + lm;
        bfv[j] = *(const short8*)(Bsc + r * 64 + (((kk * 4 + lq) ^ (r & 7)) << 3));
      }
#pragma unroll
      for (int i = 0; i < 4; ++i)
#pragma unroll
        for (int j = 0; j < 4; ++j)
          acc[i][j] = __builtin_amdgcn_mfma_f32_16x16x32_bf16(af[i], bfv[j], acc[i][j], 0, 0, 0);
    }
  }

  // bias + GN3 stats (cpg=16: fragment i = group mt*4+i)
  float s1[4] = {0.f, 0.f, 0.f, 0.f};
  float s2[4] = {0.f, 0.f, 0.f, 0.f};
#pragma unroll
  for (int i = 0; i < 4; ++i) {
    int mbase = mt * 64 + i * 16 + lq * 4;
#pragma unroll
    for (int e = 0; e < 4; ++e) {
      float bv = bias[mbase + e];
#pragma unroll
      for (int j = 0; j < 4; ++j) {
        acc[i][j][e] += bv;
        float v = acc[i][j][e];
        s1[i] += v; s2[i] += v * v;
      }
    }
  }
#pragma unroll
  for (int i = 0; i < 4; ++i) {
#pragma unroll
    for (int off = 32; off > 0; off >>= 1) {
      s1[i] += __shfl_xor(s1[i], off);
      s2[i] += __shfl_xor(s2[i], off);
    }
  }
  if (lane == 0) {
#pragma unroll
    for (int i = 0; i < 4; ++i) {
      int g = mt * 4 + i;
      atomicAdd(&raw3[(bb * 32 + g) * 2],     s1[i]);
      atomicAdd(&raw3[(bb * 32 + g) * 2 + 1], s2[i]);
    }
    __threadfence();                    // drain this lane's atomics device-wide
  }

  // ---- software grid barrier (one-shot; bar zeroed by host memset) ----
  __syncthreads();                      // all waves' atomics issued+drained
  if (tid == 0) {
    __hip_atomic_fetch_add(bar, 1, __ATOMIC_RELEASE, __HIP_MEMORY_SCOPE_AGENT);
    while (__hip_atomic_load(bar, __ATOMIC_ACQUIRE, __HIP_MEMORY_SCOPE_AGENT) < 512) {
      __builtin_amdgcn_s_sleep(8);
    }
  }
  __syncthreads();

  // in-register GN + ReLU -> outMixed (stats read with agent-scope atomics)
#pragma unroll
  for (int i = 0; i < 4; ++i) {
    int g = mt * 4 + i;
    float sA = __hip_atomic_load(&raw3[(bb * 32 + g) * 2],     __ATOMIC_RELAXED,
                                 __HIP_MEMORY_SCOPE_AGENT);
    float sB = __hip_atomic_load(&raw3[(bb * 32 + g) * 2 + 1], __ATOMIC_RELAXED,
                                 __HIP_MEMORY_SCOPE_AGENT);
    float mu = sA * (1.f / 32768.f);
    float rs = 1.0f / sqrtf(sB * (1.f / 32768.f) - mu * mu + 1e-5f);
#pragma unroll
    for (int e = 0; e < 4; ++e) {
      int m = mt * 64 + i * 16 + lq * 4 + e;
      float ga = g3[m], bt = be3[m];
      float* yp = out + ((size_t)bb * 512 + m) * 2048 + nt * 128 + w * 64 + lm;
#pragma unroll
      for (int j = 0; j < 4; ++j)
        yp[j * 16] = relu((acc[i][j][e] - mu) * rs * ga + bt);
    }
  }
}

// ---------------------------------------------------------------------------
// 9. GN+ReLU from Y12 rows; mu/rs computed inline from raw sums (statsFin12
//    folded in). bf16 transposed into X3T; optional fp32 copy to featOut.
__global__ void normT_kernel(const float* __restrict__ Y, const float* __restrict__ raw,
                             float inv_n,
                             const float* __restrict__ gamma, const float* __restrict__ beta,
                             int rowsB, int chBase, int C, int gShift,
                             u16* __restrict__ X3T, int colBase,
                             float* __restrict__ featOut) {
  __shared__ u16 tile[64][65];           // [t_local][c_local]
  int b = blockIdx.z, c0 = blockIdx.y * 64, t0 = blockIdx.x * 64;
  const float* yb = Y + ((size_t)b * rowsB + chBase) * 2048;
  for (int i = threadIdx.x; i < 4096; i += 256) {
    int r = i >> 6, cc = i & 63;         // r: channel-local, cc: t-local
    int ch = c0 + r;
    int gI = (b * 32 + (ch >> gShift)) * 2;
    float mu = raw[gI] * inv_n;
    float var = raw[gI + 1] * inv_n - mu * mu;
    float rs = 1.0f / sqrtf(var + 1e-5f);
    float v = yb[(size_t)ch * 2048 + t0 + cc];
    float o = relu((v - mu) * rs * gamma[ch] + beta[ch]);
    tile[cc][r] = f2bf(o);
    if (featOut) featOut[((size_t)b * C + ch) * 2048 + t0 + cc] = o;
  }
  __syncthreads();
  for (int i = threadIdx.x; i < 4096; i += 256) {
    int r = i >> 6, cc = i & 63;         // r: t-local, cc: c-local
    X3T[((size_t)b * 2048 + t0 + r) * 2048 + colBase + c0 + cc] = tile[r][cc];
  }
}

// ---------------------------------------------------------------------------
extern "C" void kernel_launch(void* const* d_in, const int* in_sizes, int n_in,
                              void* d_out, int out_size, void* d_ws, size_t ws_size,
                              hipStream_t stream) {
  const float* feature = (const float*)d_in[0];
  const float* frame   = (const float*)d_in[1];
  const float* W1 = (const float*)d_in[2];
  const float* b1 = (const float*)d_in[3];
  const float* g1 = (const float*)d_in[4];
  const float* be1 = (const float*)d_in[5];
  const float* W2 = (const float*)d_in[6];
  const float* b2 = (const float*)d_in[7];
  const float* g2 = (const float*)d_in[8];
  const float* be2 = (const float*)d_in[9];
  const float* W3 = (const float*)d_in[10];
  const float* b3 = (const float*)d_in[11];
  const float* g3 = (const float*)d_in[12];
  const float* be3 = (const float*)d_in[13];

  char* ws = (char*)d_ws;
  // Layout / stream-ordered aliasing (r2-verified):
  //   X3T   [0, 32MiB)            bf16 (B,2048t,2048c)
  //   Y12f  [32MiB, 80MiB)        f32 (B,1536,2048) = GEMM1+2 output
  //   W3b   [64MiB, 66MiB)        bf16, written after normT2 (Y12 dead)
  //   partD [48MiB, +256KiB)      f64, dead before gemm12 writes Y12
  //   featT [80MiB, 88MiB)        bf16 (B,2048,512)
  //   W12b  [88MiB, +1.5MiB)      bf16 stacked W1;W2
  //   small tail after W12b (cdf/idx/raw1/raw2/raw3/bar)
  u16*    X3T   = (u16*)(ws + 0);
  float*  Y12f  = (float*)(ws + 33554432);
  u16*    W3b   = (u16*)(ws + 67108864);
  double* partD = (double*)(ws + 50331648);
  u16*    featT = (u16*)(ws + 83886080);
  u16*    W12b  = (u16*)(ws + 92274688);
  int*    cdf   = (int*)(ws + 93847552);
  int*    idx   = (int*)(ws + 93863936);
  float*  raw1  = (float*)(ws + 93872128);
  float*  raw2  = (float*)(ws + 93873152);
  float*  raw3  = (float*)(ws + 93874176);
  int*    bar   = (int*)(ws + 93875200);

  float* outMixed = (float*)d_out;                       // (B,512,2048) fp32
  float* outFeat  = outMixed + (size_t)4 * 512 * 2048;   // (B,1024,2048) fp32

  hipMemsetAsync(raw1, 0, 4 * 1024, stream);             // raw1/raw2/raw3/bar

  colmean_part_kernel<<<dim3(16, 8), 256, 0, stream>>>(frame, partD);
  scanD_kernel<<<1, 256, 0, stream>>>(partD, cdf);
  argmin_kernel<<<2048, 256, 0, stream>>>(cdf, idx);
  gatherT_kernel<<<dim3(8, 32, 4), 256, 0, stream>>>(frame, idx, X3T);
  transposeCT_kernel<<<dim3(8, 32, 4), 256, 0, stream>>>(feature, featT);

  convW12_kernel<<<3072, 256, 0, stream>>>(W1, W2, W12b);
  gemm12_kernel<<<dim3(16, 24, 4), 128, 0, stream>>>(W12b, featT, b1, b2, Y12f,
                                                     raw1, raw2);
  normT_kernel<<<dim3(32, 8, 4), 256, 0, stream>>>(Y12f, raw1, 1.f / 32768.f,
                                                   g1, be1, 1536, 0, 512, 4,
                                                   X3T, 1536, (float*)nullptr);
  normT_kernel<<<dim3(32, 16, 4), 256, 0, stream>>>(Y12f, raw2, 1.f / 65536.f,
                                                    g2, be2, 1536, 512, 1024, 5,
                                                    X3T, 512, outFeat);
  convW_kernel<<<4096, 256, 0, stream>>>(W3, W3b, 1048576);
  gemm3f_kernel<<<dim3(16, 8, 4), 128, 0, stream>>>(W3b, X3T, b3, g3, be3,
                                                    raw3, bar, outMixed);
}

// Round 6
// 335.098 us; speedup vs baseline: 1.0824x; 1.0824x over previous
//
#include <hip/hip_runtime.h>

typedef unsigned short u16;
typedef unsigned int   u32;
typedef __attribute__((ext_vector_type(8))) short short8;
typedef __attribute__((ext_vector_type(4))) float f32x4;

__device__ __forceinline__ float bf2f(u16 v) {
  return __uint_as_float(((u32)v) << 16);
}
__device__ __forceinline__ u16 f2bf(float f) {
  u32 u = __float_as_uint(f);
  u32 r = (u + 0x7FFFu + ((u >> 16) & 1u)) >> 16;   // RNE
  return (u16)r;
}
// NaN-propagating ReLU (fmaxf(NaN,0)=0 would hide poison as zeros)
__device__ __forceinline__ float relu(float x) { return x < 0.f ? 0.f : x; }

// async global->LDS, 16B/lane; LDS dest = wave-uniform base + lane*16
__device__ __forceinline__ void gld16(const void* g, void* l) {
  __builtin_amdgcn_global_load_lds((const __attribute__((address_space(1))) u32*)g,
                                   (__attribute__((address_space(3))) u32*)l, 16, 0, 0);
}

// ---------------------------------------------------------------------------
// 1a. partial column sums of frame batch 0: chunk ch sums c in [ch*64,ch*64+64)
__global__ void colmean_part_kernel(const float* __restrict__ frame,
                                    double* __restrict__ partD) {
  int tf = blockIdx.x * 256 + threadIdx.x;           // 4096
  int ch = blockIdx.y;                               // 8 chunks
  const float* f0 = frame + tf + (size_t)ch * 64 * 4096;
  double s = 0.0;
  for (int c = 0; c < 64; ++c) s += (double)f0[(size_t)c * 4096];
  partD[ch * 4096 + tf] = s;
}

// ---------------------------------------------------------------------------
// 2. f64: mean = (in-order chunk combine)/512; S = sum; q = mean/S; cumsum;
//    cdf = min(int(c*2048), 2047).
__global__ void scanD_kernel(const double* __restrict__ partD, int* __restrict__ cdf) {
  __shared__ double part[256];
  __shared__ double base[256];
  __shared__ double Ss;
  int tid = threadIdx.x;
  double loc[16];
  double s = 0.0;
#pragma unroll
  for (int i = 0; i < 16; ++i) {
    int tf = tid * 16 + i;
    double m = 0.0;
#pragma unroll
    for (int ch = 0; ch < 8; ++ch) m += partD[ch * 4096 + tf];  // in c-order
    loc[i] = m / 512.0;
    s += loc[i];
  }
  part[tid] = s;
  __syncthreads();
  if (tid == 0) {
    double t = 0.0;
    for (int i = 0; i < 256; ++i) t += part[i];
    Ss = t;
  }
  __syncthreads();
  double S = Ss;
  s = 0.0;
#pragma unroll
  for (int i = 0; i < 16; ++i) { loc[i] = loc[i] / S; s += loc[i]; }
  part[tid] = s;
  __syncthreads();
  if (tid == 0) {
    double c = 0.0;
    for (int i = 0; i < 256; ++i) { base[i] = c; c += part[i]; }
  }
  __syncthreads();
  double c = base[tid];
#pragma unroll
  for (int i = 0; i < 16; ++i) {
    c += loc[i];
    int iv = (int)(c * 2048.0);                      // trunc = astype(int32)
    cdf[tid * 16 + i] = iv < 2047 ? iv : 2047;
  }
}

// ---------------------------------------------------------------------------
// 3. idx[target] = first argmin_j |cdf[j]-target|
__global__ void argmin_kernel(const int* __restrict__ cdf, int* __restrict__ idx) {
  __shared__ int sd[256], sj[256];
  int target = blockIdx.x;                            // 2048 blocks
  int tid = threadIdx.x;
  int best = 0x7fffffff, bj = 0x7fffffff;
  for (int j = tid; j < 4096; j += 256) {
    int d = cdf[j] - target; d = d < 0 ? -d : d;
    if (d < best) { best = d; bj = j; }               // strict < keeps first
  }
  sd[tid] = best; sj[tid] = bj;
  __syncthreads();
  for (int s = 128; s > 0; s >>= 1) {
    if (tid < s) {
      if (sd[tid+s] < sd[tid] || (sd[tid+s] == sd[tid] && sj[tid+s] < sj[tid])) {
        sd[tid] = sd[tid+s]; sj[tid] = sj[tid+s];
      }
    }
    __syncthreads();
  }
  if (tid == 0) idx[target] = sj[0];
}

// ---------------------------------------------------------------------------
// 4. gather transposed: X3T[b][t][c] = bf16(frame[b][c][idx[t]]), c in [0,512)
__global__ void gatherT_kernel(const float* __restrict__ frame, const int* __restrict__ idx,
                               u16* __restrict__ X3T) {
  __shared__ u16 tile[64][65];
  __shared__ int sidx[64];
  int cb = blockIdx.x * 64, t0 = blockIdx.y * 64, b = blockIdx.z;
  int tid = threadIdx.x;
  if (tid < 64) {
    int it = idx[t0 + tid];
    sidx[tid] = it < 0 ? 0 : (it > 4095 ? 4095 : it);
  }
  __syncthreads();
  const float* fb = frame + (size_t)b * 512 * 4096;
  for (int i = tid; i < 4096; i += 256) {
    int r = i >> 6, tt = i & 63;        // r = c-local, tt = t-local
    tile[tt][r] = f2bf(fb[(size_t)(cb + r) * 4096 + sidx[tt]]);
  }
  __syncthreads();
  u16* xb = X3T + (size_t)b * 2048 * 2048;
  for (int i = tid; i < 4096; i += 256) {
    int r = i >> 6, cc = i & 63;        // r = t-local, cc = c-local
    xb[(size_t)(t0 + r) * 2048 + cb + cc] = tile[r][cc];
  }
}

// ---------------------------------------------------------------------------
// 5. feature (B,512c,2048t) fp32 -> featT (B,2048t,512c) bf16, LDS 64x64
__global__ void transposeCT_kernel(const float* __restrict__ X, u16* __restrict__ XT) {
  __shared__ u16 tile[64][65];
  int cb = blockIdx.x * 64, t0 = blockIdx.y * 64, b = blockIdx.z;
  int tid = threadIdx.x;
  const float* xb = X + (size_t)b * 512 * 2048;
  for (int i = tid; i < 4096; i += 256) {
    int r = i >> 6, tt = i & 63;        // coalesced along t
    tile[tt][r] = f2bf(xb[(size_t)(cb + r) * 2048 + t0 + tt]);
  }
  __syncthreads();
  u16* xtb = XT + (size_t)b * 2048 * 512;
  for (int i = tid; i < 4096; i += 256) {
    int r = i >> 6, cc = i & 63;
    xtb[(size_t)(t0 + r) * 512 + cb + cc] = tile[r][cc];
  }
}

// ---------------------------------------------------------------------------
// 6. W1 (262144) ++ W2 (524288) fp32 -> W12b bf16 (stacked rows, K=512)
__global__ void convW12_kernel(const float* __restrict__ W1, const float* __restrict__ W2,
                               u16* __restrict__ dst) {
  int i = blockIdx.x * 256 + threadIdx.x;            // 786432
  dst[i] = f2bf(i < 262144 ? W1[i] : W2[i - 262144]);
}
__global__ void convW_kernel(const float* __restrict__ src, u16* __restrict__ dst, int n) {
  int i = blockIdx.x * 256 + threadIdx.x;
  if (i < n) dst[i] = f2bf(src[i]);
}

// ---------------------------------------------------------------------------
// 7a. fused GEMM1+2 (r2-verified): Y12 + bias; GN1/GN2 stage-1 stats fused.
//     M=1536, N=2048, K=512. 64x128 tile, 2 waves. Conflict-free both-sides
//     16B-slot XOR swizzle (slot ^= (row>>1)&3).
__global__ __launch_bounds__(128) void gemm12_kernel(
    const u16* __restrict__ A, const u16* __restrict__ Bt,
    const float* __restrict__ b1, const float* __restrict__ b2,
    float* __restrict__ Y, float* __restrict__ raw1, float* __restrict__ raw2)
{
  const int K = 512;
  __shared__ short As[2][2048];   // [buf][64 m][32 k]
  __shared__ short Bs[2][4096];   // [buf][128 n][32 k]
  const int tid = threadIdx.x;
  const int lane = tid & 63;
  const int w = tid >> 6;
  const int nt = blockIdx.x, mt = blockIdx.y, bb = blockIdx.z;
  const u16* Ab = A + (size_t)mt * 64 * K;
  const u16* Bb = Bt + ((size_t)bb * 2048 + (size_t)nt * 128) * K;
  const int lm = lane & 15, lq = lane >> 4;
  f32x4 acc[4][4] = {};

  auto stage = [&](int buf, int kt) {
#pragma unroll
    for (int p = 0; p < 2; ++p) {
      int chunk = tid + 128 * p;
      int row = chunk >> 2;
      int ko = ((chunk & 3) ^ ((row >> 1) & 3)) << 3;   // source pre-swizzle
      gld16(Ab + (size_t)row * K + kt + ko, (char*)As[buf] + chunk * 16);
    }
#pragma unroll
    for (int p = 0; p < 4; ++p) {
      int chunk = tid + 128 * p;
      int row = chunk >> 2;
      int ko = ((chunk & 3) ^ ((row >> 1) & 3)) << 3;
      gld16(Bb + (size_t)row * K + kt + ko, (char*)Bs[buf] + chunk * 16);
    }
  };

  stage(0, 0);
  for (int s = 0; s < 16; ++s) {
    int cur = s & 1;
    __syncthreads();
    if (s + 1 < 16) stage(cur ^ 1, (s + 1) << 5);
    short8 af[4], bfv[4];
#pragma unroll
    for (int i = 0; i < 4; ++i) {
      int r = i * 16 + lm;
      af[i] = *(const short8*)(As[cur] + r * 32 + ((lq ^ ((r >> 1) & 3)) << 3));
    }
#pragma unroll
    for (int j = 0; j < 4; ++j) {
      int r = w * 64 + j * 16 + lm;
      bfv[j] = *(const short8*)(Bs[cur] + r * 32 + ((lq ^ ((r >> 1) & 3)) << 3));
    }
#pragma unroll
    for (int i = 0; i < 4; ++i)
#pragma unroll
      for (int j = 0; j < 4; ++j)
        acc[i][j] = __builtin_amdgcn_mfma_f32_16x16x32_bf16(af[i], bfv[j], acc[i][j], 0, 0, 0);
  }

  float s1[4] = {0.f, 0.f, 0.f, 0.f};
  float s2[4] = {0.f, 0.f, 0.f, 0.f};
#pragma unroll
  for (int i = 0; i < 4; ++i) {
    int mbase = mt * 64 + i * 16 + lq * 4;
#pragma unroll
    for (int e = 0; e < 4; ++e) {
      int m = mbase + e;
      float bv = m < 512 ? b1[m] : b2[m - 512];
      float* yp = Y + ((size_t)bb * 1536 + m) * 2048 + nt * 128 + w * 64 + lm;
#pragma unroll
      for (int j = 0; j < 4; ++j) {
        float v = acc[i][j][e] + bv;
        yp[j * 16] = v;
        s1[i] += v; s2[i] += v * v;
      }
    }
  }
#pragma unroll
  for (int i = 0; i < 4; ++i) {
#pragma unroll
    for (int off = 32; off > 0; off >>= 1) {
      s1[i] += __shfl_xor(s1[i], off);
      s2[i] += __shfl_xor(s2[i], off);
    }
  }
  if (lane == 0) {
    if (mt < 8) {                                  // GN1: cpg=16, frag = 1 group
#pragma unroll
      for (int i = 0; i < 4; ++i) {
        int g = mt * 4 + i;
        atomicAdd(&raw1[(bb * 32 + g) * 2],     s1[i]);
        atomicAdd(&raw1[(bb * 32 + g) * 2 + 1], s2[i]);
      }
    } else {                                       // GN2: cpg=32, 2 frags = 1 group
#pragma unroll
      for (int i = 0; i < 2; ++i) {
        int g = (mt - 8) * 2 + i;
        atomicAdd(&raw2[(bb * 32 + g) * 2],     s1[2 * i] + s1[2 * i + 1]);
        atomicAdd(&raw2[(bb * 32 + g) * 2 + 1], s2[2 * i] + s2[2 * i + 1]);
      }
    }
  }
}

// ---------------------------------------------------------------------------
// 7b. fused GEMM3 + GN3 + ReLU via SOFTWARE grid barrier (r5-proven barrier,
//     r5 occupancy bug fixed). Full-K, BK=64, M=512, N=2048, K=2048.
//     64x128 tile, 256 threads (4 waves; wave w owns 64m x 32n quarter):
//     512 blocks x 4 waves = 8 waves/CU (2/SIMD) — same wave occupancy as the
//     42us split-K gemm3s (r5 had 128 threads -> 1/SIMD -> 146us).
//     48KiB LDS -> capacity 3/CU = 768 blocks >= 512 -> co-resident, no
//     deadlock. Stats atomics -> barrier -> shfl-broadcast stats -> GN+ReLU.
//     Replaces gemm3s+stats3p+statsFin+norm3 (~100MB Y3p traffic, 3 launches).
__global__ __launch_bounds__(256) void gemm3f_kernel(
    const u16* __restrict__ A, const u16* __restrict__ Bt,
    const float* __restrict__ bias,
    const float* __restrict__ g3, const float* __restrict__ be3,
    float* __restrict__ raw3, int* __restrict__ bar,
    float* __restrict__ out)
{
  const int K = 2048;
  __shared__ char smem[49152];          // As[2][64][64] 16KB | Bs[2][128][64] 32KB
  short* As0 = (short*)smem;            // As[buf] = As0 + buf*4096
  short* Bs0 = (short*)(smem + 16384);  // Bs[buf] = Bs0 + buf*8192
  const int tid = threadIdx.x;
  const int lane = tid & 63;
  const int w = tid >> 6;               // 4 waves
  const int nt = blockIdx.x, mt = blockIdx.y, bb = blockIdx.z;
  const u16* Ab = A + (size_t)mt * 64 * K;
  const u16* Bb = Bt + ((size_t)bb * 2048 + (size_t)nt * 128) * K;
  const int lm = lane & 15, lq = lane >> 4;
  f32x4 acc[4][2] = {};                 // 4 m-frags x 2 n-frags (64m x 32n)

  // rows are 128B = 8x16B slots; LDS linear, source slot pre-swizzled by
  // seg ^ (row&7); ds_read applies the same XOR (r5-verified numerics).
  auto stage = [&](int buf, int kt) {
#pragma unroll
    for (int p = 0; p < 2; ++p) {
      int chunk = tid + 256 * p;                 // 512 chunks: 64 rows x 8
      int row = chunk >> 3, seg = chunk & 7;
      gld16(Ab + (size_t)row * K + kt + ((seg ^ (row & 7)) << 3),
            (char*)(As0 + buf * 4096) + chunk * 16);
    }
#pragma unroll
    for (int p = 0; p < 4; ++p) {
      int chunk = tid + 256 * p;                 // 1024 chunks: 128 rows x 8
      int row = chunk >> 3, seg = chunk & 7;
      gld16(Bb + (size_t)row * K + kt + ((seg ^ (row & 7)) << 3),
            (char*)(Bs0 + buf * 8192) + chunk * 16);
    }
  };

  stage(0, 0);
  for (int s = 0; s < 32; ++s) {
    int cur = s & 1;
    __syncthreads();
    if (s + 1 < 32) stage(cur ^ 1, (s + 1) << 6);
    const short* Asc = As0 + cur * 4096;
    const short* Bsc = Bs0 + cur * 8192;
#pragma unroll
    for (int kk = 0; kk < 2; ++kk) {
      short8 af[4], bfv[2];
#pragma unroll
      for (int i = 0; i < 4; ++i) {
        int r = i * 16 + lm;
        af[i] = *(const short8*)(Asc + r * 64 + (((kk * 4 + lq) ^ (r & 7)) << 3));
      }
#pragma unroll
      for (int j = 0; j < 2; ++j) {
        int r = w * 32 + j * 16 + lm;
        bfv[j] = *(const short8*)(Bsc + r * 64 + (((kk * 4 + lq) ^ (r & 7)) << 3));
      }
#pragma unroll
      for (int i = 0; i < 4; ++i)
#pragma unroll
        for (int j = 0; j < 2; ++j)
          acc[i][j] = __builtin_amdgcn_mfma_f32_16x16x32_bf16(af[i], bfv[j], acc[i][j], 0, 0, 0);
    }
  }

  // bias + GN3 stats (cpg=16: m-fragment i = group mt*4+i; each wave holds a
  // 16ch x 32t slice of the group -> wave-reduce + atomicAdd)
  float s1[4] = {0.f, 0.f, 0.f, 0.f};
  float s2[4] = {0.f, 0.f, 0.f, 0.f};
#pragma unroll
  for (int i = 0; i < 4; ++i) {
    int mbase = mt * 64 + i * 16 + lq * 4;
#pragma unroll
    for (int e = 0; e < 4; ++e) {
      float bv = bias[mbase + e];
#pragma unroll
      for (int j = 0; j < 2; ++j) {
        acc[i][j][e] += bv;
        float v = acc[i][j][e];
        s1[i] += v; s2[i] += v * v;
      }
    }
  }
#pragma unroll
  for (int i = 0; i < 4; ++i) {
#pragma unroll
    for (int off = 32; off > 0; off >>= 1) {
      s1[i] += __shfl_xor(s1[i], off);
      s2[i] += __shfl_xor(s2[i], off);
    }
  }
  if (lane == 0) {
#pragma unroll
    for (int i = 0; i < 4; ++i) {
      int g = mt * 4 + i;
      atomicAdd(&raw3[(bb * 32 + g) * 2],     s1[i]);
      atomicAdd(&raw3[(bb * 32 + g) * 2 + 1], s2[i]);
    }
    __threadfence();                    // drain this lane's atomics device-wide
  }

  // ---- software grid barrier (one-shot; bar zeroed by host memset) ----
  __syncthreads();                      // all waves' atomics issued+drained
  if (tid == 0) {
    __hip_atomic_fetch_add(bar, 1, __ATOMIC_RELEASE, __HIP_MEMORY_SCOPE_AGENT);
    while (__hip_atomic_load(bar, __ATOMIC_ACQUIRE, __HIP_MEMORY_SCOPE_AGENT) < 512) {
      __builtin_amdgcn_s_sleep(8);
    }
  }
  __syncthreads();

  // stats: 8 agent-scope atomic loads per wave (lane<8), shfl-broadcast
  float v = 0.f;
  if (lane < 8)
    v = __hip_atomic_load(&raw3[(bb * 32 + mt * 4 + (lane >> 1)) * 2 + (lane & 1)],
                          __ATOMIC_RELAXED, __HIP_MEMORY_SCOPE_AGENT);
#pragma unroll
  for (int i = 0; i < 4; ++i) {
    float sA = __shfl(v, i * 2);
    float sB = __shfl(v, i * 2 + 1);
    float mu = sA * (1.f / 32768.f);
    float rs = 1.0f / sqrtf(sB * (1.f / 32768.f) - mu * mu + 1e-5f);
#pragma unroll
    for (int e = 0; e < 4; ++e) {
      int m = mt * 64 + i * 16 + lq * 4 + e;
      float ga = g3[m], bt = be3[m];
      float* yp = out + ((size_t)bb * 512 + m) * 2048 + nt * 128 + w * 32 + lm;
#pragma unroll
      for (int j = 0; j < 2; ++j)
        yp[j * 16] = relu((acc[i][j][e] - mu) * rs * ga + bt);
    }
  }
}

// ---------------------------------------------------------------------------
// 9. GN+ReLU from Y12 rows; mu/rs computed inline from raw sums (statsFin12
//    folded in, r5-verified). bf16 transposed into X3T; optional fp32 featOut.
__global__ void normT_kernel(const float* __restrict__ Y, const float* __restrict__ raw,
                             float inv_n,
                             const float* __restrict__ gamma, const float* __restrict__ beta,
                             int rowsB, int chBase, int C, int gShift,
                             u16* __restrict__ X3T, int colBase,
                             float* __restrict__ featOut) {
  __shared__ u16 tile[64][65];           // [t_local][c_local]
  int b = blockIdx.z, c0 = blockIdx.y * 64, t0 = blockIdx.x * 64;
  const float* yb = Y + ((size_t)b * rowsB + chBase) * 2048;
  for (int i = threadIdx.x; i < 4096; i += 256) {
    int r = i >> 6, cc = i & 63;         // r: channel-local, cc: t-local
    int ch = c0 + r;
    int gI = (b * 32 + (ch >> gShift)) * 2;
    float mu = raw[gI] * inv_n;
    float var = raw[gI + 1] * inv_n - mu * mu;
    float rs = 1.0f / sqrtf(var + 1e-5f);
    float v = yb[(size_t)ch * 2048 + t0 + cc];
    float o = relu((v - mu) * rs * gamma[ch] + beta[ch]);
    tile[cc][r] = f2bf(o);
    if (featOut) featOut[((size_t)b * C + ch) * 2048 + t0 + cc] = o;
  }
  __syncthreads();
  for (int i = threadIdx.x; i < 4096; i += 256) {
    int r = i >> 6, cc = i & 63;         // r: t-local, cc: c-local
    X3T[((size_t)b * 2048 + t0 + r) * 2048 + colBase + c0 + cc] = tile[r][cc];
  }
}

// ---------------------------------------------------------------------------
extern "C" void kernel_launch(void* const* d_in, const int* in_sizes, int n_in,
                              void* d_out, int out_size, void* d_ws, size_t ws_size,
                              hipStream_t stream) {
  const float* feature = (const float*)d_in[0];
  const float* frame   = (const float*)d_in[1];
  const float* W1 = (const float*)d_in[2];
  const float* b1 = (const float*)d_in[3];
  const float* g1 = (const float*)d_in[4];
  const float* be1 = (const float*)d_in[5];
  const float* W2 = (const float*)d_in[6];
  const float* b2 = (const float*)d_in[7];
  const float* g2 = (const float*)d_in[8];
  const float* be2 = (const float*)d_in[9];
  const float* W3 = (const float*)d_in[10];
  const float* b3 = (const float*)d_in[11];
  const float* g3 = (const float*)d_in[12];
  const float* be3 = (const float*)d_in[13];

  char* ws = (char*)d_ws;
  // Layout / stream-ordered aliasing (r2-verified):
  //   X3T   [0, 32MiB)            bf16 (B,2048t,2048c)
  //   Y12f  [32MiB, 80MiB)        f32 (B,1536,2048) = GEMM1+2 output
  //   W3b   [64MiB, 66MiB)        bf16, written after normT2 (Y12 dead)
  //   partD [48MiB, +256KiB)      f64, dead before gemm12 writes Y12
  //   featT [80MiB, 88MiB)        bf16 (B,2048,512)
  //   W12b  [88MiB, +1.5MiB)      bf16 stacked W1;W2
  //   small tail after W12b (cdf/idx/raw1/raw2/raw3/bar)
  u16*    X3T   = (u16*)(ws + 0);
  float*  Y12f  = (float*)(ws + 33554432);
  u16*    W3b   = (u16*)(ws + 67108864);
  double* partD = (double*)(ws + 50331648);
  u16*    featT = (u16*)(ws + 83886080);
  u16*    W12b  = (u16*)(ws + 92274688);
  int*    cdf   = (int*)(ws + 93847552);
  int*    idx   = (int*)(ws + 93863936);
  float*  raw1  = (float*)(ws + 93872128);
  float*  raw2  = (float*)(ws + 93873152);
  float*  raw3  = (float*)(ws + 93874176);
  int*    bar   = (int*)(ws + 93875200);

  float* outMixed = (float*)d_out;                       // (B,512,2048) fp32
  float* outFeat  = outMixed + (size_t)4 * 512 * 2048;   // (B,1024,2048) fp32

  hipMemsetAsync(raw1, 0, 4 * 1024, stream);             // raw1/raw2/raw3/bar

  colmean_part_kernel<<<dim3(16, 8), 256, 0, stream>>>(frame, partD);
  scanD_kernel<<<1, 256, 0, stream>>>(partD, cdf);
  argmin_kernel<<<2048, 256, 0, stream>>>(cdf, idx);
  gatherT_kernel<<<dim3(8, 32, 4), 256, 0, stream>>>(frame, idx, X3T);
  transposeCT_kernel<<<dim3(8, 32, 4), 256, 0, stream>>>(feature, featT);

  convW12_kernel<<<3072, 256, 0, stream>>>(W1, W2, W12b);
  gemm12_kernel<<<dim3(16, 24, 4), 128, 0, stream>>>(W12b, featT, b1, b2, Y12f,
                                                     raw1, raw2);
  normT_kernel<<<dim3(32, 8, 4), 256, 0, stream>>>(Y12f, raw1, 1.f / 32768.f,
                                                   g1, be1, 1536, 0, 512, 4,
                                                   X3T, 1536, (float*)nullptr);
  normT_kernel<<<dim3(32, 16, 4), 256, 0, stream>>>(Y12f, raw2, 1.f / 65536.f,
                                                    g2, be2, 1536, 512, 1024, 5,
                                                    X3T, 512, outFeat);
  convW_kernel<<<4096, 256, 0, stream>>>(W3, W3b, 1048576);
  gemm3f_kernel<<<dim3(16, 8, 4), 256, 0, stream>>>(W3b, X3T, b3, g3, be3,
                                                    raw3, bar, outMixed);
}

// Round 7
// 277.557 us; speedup vs baseline: 1.3068x; 1.2073x over previous
//
#include <hip/hip_runtime.h>

typedef unsigned short u16;
typedef unsigned int   u32;
typedef __attribute__((ext_vector_type(8))) short short8;
typedef __attribute__((ext_vector_type(4))) float f32x4;

__device__ __forceinline__ float bf2f(u16 v) {
  return __uint_as_float(((u32)v) << 16);
}
__device__ __forceinline__ u16 f2bf(float f) {
  u32 u = __float_as_uint(f);
  u32 r = (u + 0x7FFFu + ((u >> 16) & 1u)) >> 16;   // RNE
  return (u16)r;
}
// NaN-propagating ReLU (fmaxf(NaN,0)=0 would hide poison as zeros)
__device__ __forceinline__ float relu(float x) { return x < 0.f ? 0.f : x; }

// async global->LDS, 16B/lane; LDS dest = wave-uniform base + lane*16
__device__ __forceinline__ void gld16(const void* g, void* l) {
  __builtin_amdgcn_global_load_lds((const __attribute__((address_space(1))) u32*)g,
                                   (__attribute__((address_space(3))) u32*)l, 16, 0, 0);
}

// ---------------------------------------------------------------------------
// 1a. partial column sums of frame batch 0: chunk ch sums c in [ch*64,ch*64+64)
__global__ void colmean_part_kernel(const float* __restrict__ frame,
                                    double* __restrict__ partD) {
  int tf = blockIdx.x * 256 + threadIdx.x;           // 4096
  int ch = blockIdx.y;                               // 8 chunks
  const float* f0 = frame + tf + (size_t)ch * 64 * 4096;
  double s = 0.0;
  for (int c = 0; c < 64; ++c) s += (double)f0[(size_t)c * 4096];
  partD[ch * 4096 + tf] = s;
}

// ---------------------------------------------------------------------------
// 2. f64: mean = (in-order chunk combine)/512; S = sum; q = mean/S; cumsum;
//    cdf = min(int(c*2048), 2047).
__global__ void scanD_kernel(const double* __restrict__ partD, int* __restrict__ cdf) {
  __shared__ double part[256];
  __shared__ double base[256];
  __shared__ double Ss;
  int tid = threadIdx.x;
  double loc[16];
  double s = 0.0;
#pragma unroll
  for (int i = 0; i < 16; ++i) {
    int tf = tid * 16 + i;
    double m = 0.0;
#pragma unroll
    for (int ch = 0; ch < 8; ++ch) m += partD[ch * 4096 + tf];  // in c-order
    loc[i] = m / 512.0;
    s += loc[i];
  }
  part[tid] = s;
  __syncthreads();
  if (tid == 0) {
    double t = 0.0;
    for (int i = 0; i < 256; ++i) t += part[i];
    Ss = t;
  }
  __syncthreads();
  double S = Ss;
  s = 0.0;
#pragma unroll
  for (int i = 0; i < 16; ++i) { loc[i] = loc[i] / S; s += loc[i]; }
  part[tid] = s;
  __syncthreads();
  if (tid == 0) {
    double c = 0.0;
    for (int i = 0; i < 256; ++i) { base[i] = c; c += part[i]; }
  }
  __syncthreads();
  double c = base[tid];
#pragma unroll
  for (int i = 0; i < 16; ++i) {
    c += loc[i];
    int iv = (int)(c * 2048.0);                      // trunc = astype(int32)
    cdf[tid * 16 + i] = iv < 2047 ? iv : 2047;
  }
}

// ---------------------------------------------------------------------------
// 3. idx[target] = first argmin_j |cdf[j]-target|
__global__ void argmin_kernel(const int* __restrict__ cdf, int* __restrict__ idx) {
  __shared__ int sd[256], sj[256];
  int target = blockIdx.x;                            // 2048 blocks
  int tid = threadIdx.x;
  int best = 0x7fffffff, bj = 0x7fffffff;
  for (int j = tid; j < 4096; j += 256) {
    int d = cdf[j] - target; d = d < 0 ? -d : d;
    if (d < best) { best = d; bj = j; }               // strict < keeps first
  }
  sd[tid] = best; sj[tid] = bj;
  __syncthreads();
  for (int s = 128; s > 0; s >>= 1) {
    if (tid < s) {
      if (sd[tid+s] < sd[tid] || (sd[tid+s] == sd[tid] && sj[tid+s] < sj[tid])) {
        sd[tid] = sd[tid+s]; sj[tid] = sj[tid+s];
      }
    }
    __syncthreads();
  }
  if (tid == 0) idx[target] = sj[0];
}

// ---------------------------------------------------------------------------
// 4. gather transposed: X3T[b][t][c] = bf16(frame[b][c][idx[t]]), c in [0,512)
__global__ void gatherT_kernel(const float* __restrict__ frame, const int* __restrict__ idx,
                               u16* __restrict__ X3T) {
  __shared__ u16 tile[64][65];
  __shared__ int sidx[64];
  int cb = blockIdx.x * 64, t0 = blockIdx.y * 64, b = blockIdx.z;
  int tid = threadIdx.x;
  if (tid < 64) {
    int it = idx[t0 + tid];
    sidx[tid] = it < 0 ? 0 : (it > 4095 ? 4095 : it);
  }
  __syncthreads();
  const float* fb = frame + (size_t)b * 512 * 4096;
  for (int i = tid; i < 4096; i += 256) {
    int r = i >> 6, tt = i & 63;        // r = c-local, tt = t-local
    tile[tt][r] = f2bf(fb[(size_t)(cb + r) * 4096 + sidx[tt]]);
  }
  __syncthreads();
  u16* xb = X3T + (size_t)b * 2048 * 2048;
  for (int i = tid; i < 4096; i += 256) {
    int r = i >> 6, cc = i & 63;        // r = t-local, cc = c-local
    xb[(size_t)(t0 + r) * 2048 + cb + cc] = tile[r][cc];
  }
}

// ---------------------------------------------------------------------------
// 5. feature (B,512c,2048t) fp32 -> featT (B,2048t,512c) bf16, LDS 64x64
__global__ void transposeCT_kernel(const float* __restrict__ X, u16* __restrict__ XT) {
  __shared__ u16 tile[64][65];
  int cb = blockIdx.x * 64, t0 = blockIdx.y * 64, b = blockIdx.z;
  int tid = threadIdx.x;
  const float* xb = X + (size_t)b * 512 * 2048;
  for (int i = tid; i < 4096; i += 256) {
    int r = i >> 6, tt = i & 63;        // coalesced along t
    tile[tt][r] = f2bf(xb[(size_t)(cb + r) * 2048 + t0 + tt]);
  }
  __syncthreads();
  u16* xtb = XT + (size_t)b * 2048 * 512;
  for (int i = tid; i < 4096; i += 256) {
    int r = i >> 6, cc = i & 63;
    xtb[(size_t)(t0 + r) * 512 + cb + cc] = tile[r][cc];
  }
}

// ---------------------------------------------------------------------------
// 6. W1 (262144) ++ W2 (524288) fp32 -> W12b bf16 (stacked rows, K=512)
__global__ void convW12_kernel(const float* __restrict__ W1, const float* __restrict__ W2,
                               u16* __restrict__ dst) {
  int i = blockIdx.x * 256 + threadIdx.x;            // 786432
  dst[i] = f2bf(i < 262144 ? W1[i] : W2[i - 262144]);
}
__global__ void convW_kernel(const float* __restrict__ src, u16* __restrict__ dst, int n) {
  int i = blockIdx.x * 256 + threadIdx.x;
  if (i < n) dst[i] = f2bf(src[i]);
}

// ---------------------------------------------------------------------------
// 7a. fused GEMM1+2 (r2-verified): Y12 + bias; GN1/GN2 stage-1 stats fused.
//     M=1536, N=2048, K=512. 64x128 tile, 2 waves. Conflict-free both-sides
//     16B-slot XOR swizzle (slot ^= (row>>1)&3). 1536 blocks -> 6/CU resident.
__global__ __launch_bounds__(128) void gemm12_kernel(
    const u16* __restrict__ A, const u16* __restrict__ Bt,
    const float* __restrict__ b1, const float* __restrict__ b2,
    float* __restrict__ Y, float* __restrict__ raw1, float* __restrict__ raw2)
{
  const int K = 512;
  __shared__ short As[2][2048];   // [buf][64 m][32 k]
  __shared__ short Bs[2][4096];   // [buf][128 n][32 k]
  const int tid = threadIdx.x;
  const int lane = tid & 63;
  const int w = tid >> 6;
  const int nt = blockIdx.x, mt = blockIdx.y, bb = blockIdx.z;
  const u16* Ab = A + (size_t)mt * 64 * K;
  const u16* Bb = Bt + ((size_t)bb * 2048 + (size_t)nt * 128) * K;
  const int lm = lane & 15, lq = lane >> 4;
  f32x4 acc[4][4] = {};

  auto stage = [&](int buf, int kt) {
#pragma unroll
    for (int p = 0; p < 2; ++p) {
      int chunk = tid + 128 * p;
      int row = chunk >> 2;
      int ko = ((chunk & 3) ^ ((row >> 1) & 3)) << 3;   // source pre-swizzle
      gld16(Ab + (size_t)row * K + kt + ko, (char*)As[buf] + chunk * 16);
    }
#pragma unroll
    for (int p = 0; p < 4; ++p) {
      int chunk = tid + 128 * p;
      int row = chunk >> 2;
      int ko = ((chunk & 3) ^ ((row >> 1) & 3)) << 3;
      gld16(Bb + (size_t)row * K + kt + ko, (char*)Bs[buf] + chunk * 16);
    }
  };

  stage(0, 0);
  for (int s = 0; s < 16; ++s) {
    int cur = s & 1;
    __syncthreads();
    if (s + 1 < 16) stage(cur ^ 1, (s + 1) << 5);
    short8 af[4], bfv[4];
#pragma unroll
    for (int i = 0; i < 4; ++i) {
      int r = i * 16 + lm;
      af[i] = *(const short8*)(As[cur] + r * 32 + ((lq ^ ((r >> 1) & 3)) << 3));
    }
#pragma unroll
    for (int j = 0; j < 4; ++j) {
      int r = w * 64 + j * 16 + lm;
      bfv[j] = *(const short8*)(Bs[cur] + r * 32 + ((lq ^ ((r >> 1) & 3)) << 3));
    }
#pragma unroll
    for (int i = 0; i < 4; ++i)
#pragma unroll
      for (int j = 0; j < 4; ++j)
        acc[i][j] = __builtin_amdgcn_mfma_f32_16x16x32_bf16(af[i], bfv[j], acc[i][j], 0, 0, 0);
  }

  float s1[4] = {0.f, 0.f, 0.f, 0.f};
  float s2[4] = {0.f, 0.f, 0.f, 0.f};
#pragma unroll
  for (int i = 0; i < 4; ++i) {
    int mbase = mt * 64 + i * 16 + lq * 4;
#pragma unroll
    for (int e = 0; e < 4; ++e) {
      int m = mbase + e;
      float bv = m < 512 ? b1[m] : b2[m - 512];
      float* yp = Y + ((size_t)bb * 1536 + m) * 2048 + nt * 128 + w * 64 + lm;
#pragma unroll
      for (int j = 0; j < 4; ++j) {
        float v = acc[i][j][e] + bv;
        yp[j * 16] = v;
        s1[i] += v; s2[i] += v * v;
      }
    }
  }
#pragma unroll
  for (int i = 0; i < 4; ++i) {
#pragma unroll
    for (int off = 32; off > 0; off >>= 1) {
      s1[i] += __shfl_xor(s1[i], off);
      s2[i] += __shfl_xor(s2[i], off);
    }
  }
  if (lane == 0) {
    if (mt < 8) {                                  // GN1: cpg=16, frag = 1 group
#pragma unroll
      for (int i = 0; i < 4; ++i) {
        int g = mt * 4 + i;
        atomicAdd(&raw1[(bb * 32 + g) * 2],     s1[i]);
        atomicAdd(&raw1[(bb * 32 + g) * 2 + 1], s2[i]);
      }
    } else {                                       // GN2: cpg=32, 2 frags = 1 group
#pragma unroll
      for (int i = 0; i < 2; ++i) {
        int g = (mt - 8) * 2 + i;
        atomicAdd(&raw2[(bb * 32 + g) * 2],     s1[2 * i] + s1[2 * i + 1]);
        atomicAdd(&raw2[(bb * 32 + g) * 2 + 1], s2[2 * i] + s2[2 * i + 1]);
      }
    }
  }
}

// ---------------------------------------------------------------------------
// 7b. GEMM3 split-K x2 (r2-verified): partial[ks][b][m][n] over half-K
//     (+bias if ks==0). M=512, N=2048, K=2048. 64x128 tile, 2 waves,
//     grid.z = b*2+ks -> 1024 blocks. Conflict-free both-sides swizzle.
//     NOTE r5/r6 lesson: full-K fusion halves block count but doubles each
//     block's serialized 32-step K-chain -> 2x slower. Split-K stays.
__global__ __launch_bounds__(128) void gemm3s_kernel(
    const u16* __restrict__ A, const u16* __restrict__ Bt,
    const float* __restrict__ bias, float* __restrict__ Yp)
{
  const int K = 2048;
  __shared__ short As[2][2048];
  __shared__ short Bs[2][4096];
  const int tid = threadIdx.x;
  const int lane = tid & 63;
  const int w = tid >> 6;
  const int nt = blockIdx.x, mt = blockIdx.y;
  const int bb = blockIdx.z >> 1, ks = blockIdx.z & 1;
  const u16* Ab = A + (size_t)mt * 64 * K + ks * 1024;
  const u16* Bb = Bt + ((size_t)bb * 2048 + (size_t)nt * 128) * K + ks * 1024;
  const int lm = lane & 15, lq = lane >> 4;
  f32x4 acc[4][4] = {};

  auto stage = [&](int buf, int kt) {
#pragma unroll
    for (int p = 0; p < 2; ++p) {
      int chunk = tid + 128 * p;
      int row = chunk >> 2;
      int ko = ((chunk & 3) ^ ((row >> 1) & 3)) << 3;
      gld16(Ab + (size_t)row * K + kt + ko, (char*)As[buf] + chunk * 16);
    }
#pragma unroll
    for (int p = 0; p < 4; ++p) {
      int chunk = tid + 128 * p;
      int row = chunk >> 2;
      int ko = ((chunk & 3) ^ ((row >> 1) & 3)) << 3;
      gld16(Bb + (size_t)row * K + kt + ko, (char*)Bs[buf] + chunk * 16);
    }
  };

  stage(0, 0);
  for (int s = 0; s < 32; ++s) {
    int cur = s & 1;
    __syncthreads();
    if (s + 1 < 32) stage(cur ^ 1, (s + 1) << 5);
    short8 af[4], bfv[4];
#pragma unroll
    for (int i = 0; i < 4; ++i) {
      int r = i * 16 + lm;
      af[i] = *(const short8*)(As[cur] + r * 32 + ((lq ^ ((r >> 1) & 3)) << 3));
    }
#pragma unroll
    for (int j = 0; j < 4; ++j) {
      int r = w * 64 + j * 16 + lm;
      bfv[j] = *(const short8*)(Bs[cur] + r * 32 + ((lq ^ ((r >> 1) & 3)) << 3));
    }
#pragma unroll
    for (int i = 0; i < 4; ++i)
#pragma unroll
      for (int j = 0; j < 4; ++j)
        acc[i][j] = __builtin_amdgcn_mfma_f32_16x16x32_bf16(af[i], bfv[j], acc[i][j], 0, 0, 0);
  }
#pragma unroll
  for (int i = 0; i < 4; ++i) {
    int mbase = mt * 64 + i * 16 + lq * 4;
#pragma unroll
    for (int e = 0; e < 4; ++e) {
      int m = mbase + e;
      float bv = ks ? 0.f : bias[m];
      float* yp = Yp + ((size_t)(ks * 4 + bb) * 512 + m) * 2048 + nt * 128 + w * 64 + lm;
#pragma unroll
      for (int j = 0; j < 4; ++j)
        yp[j * 16] = acc[i][j][e] + bv;
    }
  }
}

// ---------------------------------------------------------------------------
// 8b. stage-1 for split-K Y3: reads partial pair, float4-vectorized (G13)
__global__ void stats3p_kernel(const float* __restrict__ Yp, float* __restrict__ raw) {
  int chunk = blockIdx.x, g = blockIdx.y, b = blockIdx.z, tid = threadIdx.x;
  const f32x4* base = (const f32x4*)(Yp + ((size_t)b * 512 + g * 16) * 2048
                                        + (size_t)chunk * 4096);
  float s = 0.f, ss = 0.f;
#pragma unroll
  for (int i = 0; i < 4; ++i) {
    f32x4 a = base[tid + 256 * i];
    f32x4 c = base[tid + 256 * i + 1048576];    // +4194304 floats
#pragma unroll
    for (int e = 0; e < 4; ++e) {
      float v = a[e] + c[e];
      s += v; ss += v * v;
    }
  }
  __shared__ float s1[256], s2[256];
  s1[tid] = s; s2[tid] = ss;
  __syncthreads();
  for (int st = 128; st > 0; st >>= 1) {
    if (tid < st) { s1[tid] += s1[tid + st]; s2[tid] += s2[tid + st]; }
    __syncthreads();
  }
  if (tid == 0) {
    atomicAdd(&raw[(b * 32 + g) * 2],     s1[0]);
    atomicAdd(&raw[(b * 32 + g) * 2 + 1], s2[0]);
  }
}

// ---------------------------------------------------------------------------
// 9. GN+ReLU from Y12 rows; mu/rs computed inline from raw sums (statsFin
//    folded in, r5/r6-verified). bf16 transposed into X3T; optional featOut.
__global__ void normT_kernel(const float* __restrict__ Y, const float* __restrict__ raw,
                             float inv_n,
                             const float* __restrict__ gamma, const float* __restrict__ beta,
                             int rowsB, int chBase, int C, int gShift,
                             u16* __restrict__ X3T, int colBase,
                             float* __restrict__ featOut) {
  __shared__ u16 tile[64][65];           // [t_local][c_local]
  int b = blockIdx.z, c0 = blockIdx.y * 64, t0 = blockIdx.x * 64;
  const float* yb = Y + ((size_t)b * rowsB + chBase) * 2048;
  for (int i = threadIdx.x; i < 4096; i += 256) {
    int r = i >> 6, cc = i & 63;         // r: channel-local, cc: t-local
    int ch = c0 + r;
    int gI = (b * 32 + (ch >> gShift)) * 2;
    float mu = raw[gI] * inv_n;
    float var = raw[gI + 1] * inv_n - mu * mu;
    float rs = 1.0f / sqrtf(var + 1e-5f);
    float v = yb[(size_t)ch * 2048 + t0 + cc];
    float o = relu((v - mu) * rs * gamma[ch] + beta[ch]);
    tile[cc][r] = f2bf(o);
    if (featOut) featOut[((size_t)b * C + ch) * 2048 + t0 + cc] = o;
  }
  __syncthreads();
  for (int i = threadIdx.x; i < 4096; i += 256) {
    int r = i >> 6, cc = i & 63;         // r: t-local, cc: c-local
    X3T[((size_t)b * 2048 + t0 + r) * 2048 + colBase + c0 + cc] = tile[r][cc];
  }
}

// ---------------------------------------------------------------------------
// 10. GN+ReLU for split-K Y3 partial pair -> fp32 mixed output.
//     float4-vectorized; statsFin folded in (mu/rs inline from raw3).
__global__ void norm3_kernel(const float* __restrict__ Yp, const float* __restrict__ raw,
                             const float* __restrict__ gamma, const float* __restrict__ beta,
                             float* __restrict__ out) {
  int i4 = blockIdx.x * 256 + threadIdx.x;           // 1,048,576 float4s
  int b = i4 >> 18;                                  // 262144 f4 per batch
  int ch = (i4 >> 9) & 511;                          // 512 f4 per channel row
  int gI = (b * 32 + (ch >> 4)) * 2;
  float mu = raw[gI] * (1.f / 32768.f);
  float var = raw[gI + 1] * (1.f / 32768.f) - mu * mu;
  float rs = 1.0f / sqrtf(var + 1e-5f);
  float ga = gamma[ch], bt = beta[ch];
  f32x4 a = ((const f32x4*)Yp)[i4];
  f32x4 c = ((const f32x4*)Yp)[i4 + 1048576];
  f32x4 o;
#pragma unroll
  for (int e = 0; e < 4; ++e)
    o[e] = relu((a[e] + c[e] - mu) * rs * ga + bt);
  ((f32x4*)out)[i4] = o;
}

// ---------------------------------------------------------------------------
extern "C" void kernel_launch(void* const* d_in, const int* in_sizes, int n_in,
                              void* d_out, int out_size, void* d_ws, size_t ws_size,
                              hipStream_t stream) {
  const float* feature = (const float*)d_in[0];
  const float* frame   = (const float*)d_in[1];
  const float* W1 = (const float*)d_in[2];
  const float* b1 = (const float*)d_in[3];
  const float* g1 = (const float*)d_in[4];
  const float* be1 = (const float*)d_in[5];
  const float* W2 = (const float*)d_in[6];
  const float* b2 = (const float*)d_in[7];
  const float* g2 = (const float*)d_in[8];
  const float* be2 = (const float*)d_in[9];
  const float* W3 = (const float*)d_in[10];
  const float* b3 = (const float*)d_in[11];
  const float* g3 = (const float*)d_in[12];
  const float* be3 = (const float*)d_in[13];

  char* ws = (char*)d_ws;
  // Layout / stream-ordered aliasing (r2-verified):
  //   X3T   [0, 32MiB)            bf16 (B,2048t,2048c)
  //   Y12f  [32MiB, 80MiB)        f32 (B,1536,2048) = GEMM1+2 output
  //   Y3p   [32MiB, 64MiB)        f32 split-K partial pair (after normT1/2)
  //   W3b   [64MiB, 66MiB)        bf16, written after normT2 (Y12 dead)
  //   partD [48MiB, +256KiB)      f64, dead before gemm12 writes Y12
  //   featT [80MiB, 88MiB)        bf16 (B,2048,512)
  //   W12b  [88MiB, +1.5MiB)      bf16 stacked W1;W2
  //   small tail after W12b (cdf/idx/raw1/raw2/raw3)
  u16*    X3T   = (u16*)(ws + 0);
  float*  Y12f  = (float*)(ws + 33554432);
  float*  Y3p   = (float*)(ws + 33554432);
  u16*    W3b   = (u16*)(ws + 67108864);
  double* partD = (double*)(ws + 50331648);
  u16*    featT = (u16*)(ws + 83886080);
  u16*    W12b  = (u16*)(ws + 92274688);
  int*    cdf   = (int*)(ws + 93847552);
  int*    idx   = (int*)(ws + 93863936);
  float*  raw1  = (float*)(ws + 93872128);
  float*  raw2  = (float*)(ws + 93873152);
  float*  raw3  = (float*)(ws + 93874176);

  float* outMixed = (float*)d_out;                       // (B,512,2048) fp32
  float* outFeat  = outMixed + (size_t)4 * 512 * 2048;   // (B,1024,2048) fp32

  hipMemsetAsync(raw1, 0, 3 * 1024, stream);             // raw1/raw2/raw3

  colmean_part_kernel<<<dim3(16, 8), 256, 0, stream>>>(frame, partD);
  scanD_kernel<<<1, 256, 0, stream>>>(partD, cdf);
  argmin_kernel<<<2048, 256, 0, stream>>>(cdf, idx);
  gatherT_kernel<<<dim3(8, 32, 4), 256, 0, stream>>>(frame, idx, X3T);
  transposeCT_kernel<<<dim3(8, 32, 4), 256, 0, stream>>>(feature, featT);

  convW12_kernel<<<3072, 256, 0, stream>>>(W1, W2, W12b);
  gemm12_kernel<<<dim3(16, 24, 4), 128, 0, stream>>>(W12b, featT, b1, b2, Y12f,
                                                     raw1, raw2);
  normT_kernel<<<dim3(32, 8, 4), 256, 0, stream>>>(Y12f, raw1, 1.f / 32768.f,
                                                   g1, be1, 1536, 0, 512, 4,
                                                   X3T, 1536, (float*)nullptr);
  normT_kernel<<<dim3(32, 16, 4), 256, 0, stream>>>(Y12f, raw2, 1.f / 65536.f,
                                                    g2, be2, 1536, 512, 1024, 5,
                                                    X3T, 512, outFeat);
  convW_kernel<<<4096, 256, 0, stream>>>(W3, W3b, 1048576);
  gemm3s_kernel<<<dim3(16, 8, 8), 128, 0, stream>>>(W3b, X3T, b3, Y3p);
  stats3p_kernel<<<dim3(8, 32, 4), 256, 0, stream>>>(Y3p, raw3);
  norm3_kernel<<<4096, 256, 0, stream>>>(Y3p, raw3, g3, be3, outMixed);
}

// Round 8
// 266.849 us; speedup vs baseline: 1.3592x; 1.0401x over previous
//
#include <hip/hip_runtime.h>

typedef unsigned short u16;
typedef unsigned int   u32;
typedef __attribute__((ext_vector_type(8))) short short8;
typedef __attribute__((ext_vector_type(4))) short short4_t;
typedef __attribute__((ext_vector_type(4))) float f32x4;

__device__ __forceinline__ float bf2f(u16 v) {
  return __uint_as_float(((u32)v) << 16);
}
__device__ __forceinline__ u16 f2bf(float f) {
  u32 u = __float_as_uint(f);
  u32 r = (u + 0x7FFFu + ((u >> 16) & 1u)) >> 16;   // RNE
  return (u16)r;
}
// NaN-propagating ReLU (fmaxf(NaN,0)=0 would hide poison as zeros)
__device__ __forceinline__ float relu(float x) { return x < 0.f ? 0.f : x; }

// async global->LDS, 16B/lane; LDS dest = wave-uniform base + lane*16
__device__ __forceinline__ void gld16(const void* g, void* l) {
  __builtin_amdgcn_global_load_lds((const __attribute__((address_space(1))) u32*)g,
                                   (__attribute__((address_space(3))) u32*)l, 16, 0, 0);
}

// ---------------------------------------------------------------------------
// 1a. partial column sums of frame batch 0; block (0,0) also zeroes the
//     raw1/raw2/raw3 stats accumulators (768 contiguous floats) — replaces
//     the hipMemsetAsync dispatch (raws first read by gemm12, much later).
__global__ void colmean_part_kernel(const float* __restrict__ frame,
                                    double* __restrict__ partD,
                                    float* __restrict__ rawZ) {
  if (blockIdx.x == 0 && blockIdx.y == 0 && threadIdx.x < 768)
    rawZ[threadIdx.x] = 0.f;
  int tf = blockIdx.x * 256 + threadIdx.x;           // 4096
  int ch = blockIdx.y;                               // 8 chunks
  const float* f0 = frame + tf + (size_t)ch * 64 * 4096;
  double s = 0.0;
  for (int c = 0; c < 64; ++c) s += (double)f0[(size_t)c * 4096];
  partD[ch * 4096 + tf] = s;
}

// ---------------------------------------------------------------------------
// 2. f64: mean = (in-order chunk combine)/512; S = sum; q = mean/S; cumsum;
//    cdf = min(int(c*2048), 2047).
__global__ void scanD_kernel(const double* __restrict__ partD, int* __restrict__ cdf) {
  __shared__ double part[256];
  __shared__ double base[256];
  __shared__ double Ss;
  int tid = threadIdx.x;
  double loc[16];
  double s = 0.0;
#pragma unroll
  for (int i = 0; i < 16; ++i) {
    int tf = tid * 16 + i;
    double m = 0.0;
#pragma unroll
    for (int ch = 0; ch < 8; ++ch) m += partD[ch * 4096 + tf];  // in c-order
    loc[i] = m / 512.0;
    s += loc[i];
  }
  part[tid] = s;
  __syncthreads();
  if (tid == 0) {
    double t = 0.0;
    for (int i = 0; i < 256; ++i) t += part[i];
    Ss = t;
  }
  __syncthreads();
  double S = Ss;
  s = 0.0;
#pragma unroll
  for (int i = 0; i < 16; ++i) { loc[i] = loc[i] / S; s += loc[i]; }
  part[tid] = s;
  __syncthreads();
  if (tid == 0) {
    double c = 0.0;
    for (int i = 0; i < 256; ++i) { base[i] = c; c += part[i]; }
  }
  __syncthreads();
  double c = base[tid];
#pragma unroll
  for (int i = 0; i < 16; ++i) {
    c += loc[i];
    int iv = (int)(c * 2048.0);                      // trunc = astype(int32)
    cdf[tid * 16 + i] = iv < 2047 ? iv : 2047;
  }
}

// ---------------------------------------------------------------------------
// 3. idx[target] = first argmin_j |cdf[j]-target|
__global__ void argmin_kernel(const int* __restrict__ cdf, int* __restrict__ idx) {
  __shared__ int sd[256], sj[256];
  int target = blockIdx.x;                            // 2048 blocks
  int tid = threadIdx.x;
  int best = 0x7fffffff, bj = 0x7fffffff;
  for (int j = tid; j < 4096; j += 256) {
    int d = cdf[j] - target; d = d < 0 ? -d : d;
    if (d < best) { best = d; bj = j; }               // strict < keeps first
  }
  sd[tid] = best; sj[tid] = bj;
  __syncthreads();
  for (int s = 128; s > 0; s >>= 1) {
    if (tid < s) {
      if (sd[tid+s] < sd[tid] || (sd[tid+s] == sd[tid] && sj[tid+s] < sj[tid])) {
        sd[tid] = sd[tid+s]; sj[tid] = sj[tid+s];
      }
    }
    __syncthreads();
  }
  if (tid == 0) idx[target] = sj[0];
}

// ---------------------------------------------------------------------------
// 4+5 merged. which = blockIdx.z>>2:
//   0: gather    X3T[b][t][c] = bf16(frame[b][c][idx[t]]), c in [0,512)
//   1: transpose featT[b][t][c] = bf16(feature[b][c][t])
//   Same grid shape per path as the two r7-verified kernels; code identical.
__global__ void gatherTrans_kernel(const float* __restrict__ frame,
                                   const float* __restrict__ feature,
                                   const int* __restrict__ idx,
                                   u16* __restrict__ X3T, u16* __restrict__ featT) {
  __shared__ u16 tile[64][65];
  __shared__ int sidx[64];
  int cb = blockIdx.x * 64, t0 = blockIdx.y * 64;
  int b = blockIdx.z & 3, which = blockIdx.z >> 2;
  int tid = threadIdx.x;
  if (which == 0) {
    if (tid < 64) {
      int it = idx[t0 + tid];
      sidx[tid] = it < 0 ? 0 : (it > 4095 ? 4095 : it);
    }
    __syncthreads();
    const float* fb = frame + (size_t)b * 512 * 4096;
    for (int i = tid; i < 4096; i += 256) {
      int r = i >> 6, tt = i & 63;        // r = c-local, tt = t-local
      tile[tt][r] = f2bf(fb[(size_t)(cb + r) * 4096 + sidx[tt]]);
    }
    __syncthreads();
    u16* xb = X3T + (size_t)b * 2048 * 2048;
    for (int i = tid; i < 4096; i += 256) {
      int r = i >> 6, cc = i & 63;        // r = t-local, cc = c-local
      xb[(size_t)(t0 + r) * 2048 + cb + cc] = tile[r][cc];
    }
  } else {
    const float* xb = feature + (size_t)b * 512 * 2048;
    for (int i = tid; i < 4096; i += 256) {
      int r = i >> 6, tt = i & 63;        // coalesced along t
      tile[tt][r] = f2bf(xb[(size_t)(cb + r) * 2048 + t0 + tt]);
    }
    __syncthreads();
    u16* xtb = featT + (size_t)b * 2048 * 512;
    for (int i = tid; i < 4096; i += 256) {
      int r = i >> 6, cc = i & 63;
      xtb[(size_t)(t0 + r) * 512 + cb + cc] = tile[r][cc];
    }
  }
}

// ---------------------------------------------------------------------------
// 6. weight conversion, float4-vectorized (boundaries all %4==0)
__global__ void convW12_kernel(const float* __restrict__ W1, const float* __restrict__ W2,
                               u16* __restrict__ dst) {
  int i = (blockIdx.x * 256 + threadIdx.x) * 4;      // 786432 total, grid 768
  f32x4 v = *(const f32x4*)(i < 262144 ? W1 + i : W2 + (i - 262144));
  short4_t o;
#pragma unroll
  for (int e = 0; e < 4; ++e) o[e] = (short)f2bf(v[e]);
  *(short4_t*)(dst + i) = o;
}
__global__ void convW_kernel(const float* __restrict__ src, u16* __restrict__ dst) {
  int i = (blockIdx.x * 256 + threadIdx.x) * 4;      // 1048576 total, grid 1024
  f32x4 v = *(const f32x4*)(src + i);
  short4_t o;
#pragma unroll
  for (int e = 0; e < 4; ++e) o[e] = (short)f2bf(v[e]);
  *(short4_t*)(dst + i) = o;
}

// ---------------------------------------------------------------------------
// 7a. fused GEMM1+2 (r2/r7-verified): Y12 + bias; GN1/GN2 stage-1 stats fused.
//     M=1536, N=2048, K=512. 64x128 tile, 2 waves. Conflict-free both-sides
//     16B-slot XOR swizzle (slot ^= (row>>1)&3). 1536 blocks -> 6/CU resident.
__global__ __launch_bounds__(128) void gemm12_kernel(
    const u16* __restrict__ A, const u16* __restrict__ Bt,
    const float* __restrict__ b1, const float* __restrict__ b2,
    float* __restrict__ Y, float* __restrict__ raw1, float* __restrict__ raw2)
{
  const int K = 512;
  __shared__ short As[2][2048];   // [buf][64 m][32 k]
  __shared__ short Bs[2][4096];   // [buf][128 n][32 k]
  const int tid = threadIdx.x;
  const int lane = tid & 63;
  const int w = tid >> 6;
  const int nt = blockIdx.x, mt = blockIdx.y, bb = blockIdx.z;
  const u16* Ab = A + (size_t)mt * 64 * K;
  const u16* Bb = Bt + ((size_t)bb * 2048 + (size_t)nt * 128) * K;
  const int lm = lane & 15, lq = lane >> 4;
  f32x4 acc[4][4] = {};

  auto stage = [&](int buf, int kt) {
#pragma unroll
    for (int p = 0; p < 2; ++p) {
      int chunk = tid + 128 * p;
      int row = chunk >> 2;
      int ko = ((chunk & 3) ^ ((row >> 1) & 3)) << 3;   // source pre-swizzle
      gld16(Ab + (size_t)row * K + kt + ko, (char*)As[buf] + chunk * 16);
    }
#pragma unroll
    for (int p = 0; p < 4; ++p) {
      int chunk = tid + 128 * p;
      int row = chunk >> 2;
      int ko = ((chunk & 3) ^ ((row >> 1) & 3)) << 3;
      gld16(Bb + (size_t)row * K + kt + ko, (char*)Bs[buf] + chunk * 16);
    }
  };

  stage(0, 0);
  for (int s = 0; s < 16; ++s) {
    int cur = s & 1;
    __syncthreads();
    if (s + 1 < 16) stage(cur ^ 1, (s + 1) << 5);
    short8 af[4], bfv[4];
#pragma unroll
    for (int i = 0; i < 4; ++i) {
      int r = i * 16 + lm;
      af[i] = *(const short8*)(As[cur] + r * 32 + ((lq ^ ((r >> 1) & 3)) << 3));
    }
#pragma unroll
    for (int j = 0; j < 4; ++j) {
      int r = w * 64 + j * 16 + lm;
      bfv[j] = *(const short8*)(Bs[cur] + r * 32 + ((lq ^ ((r >> 1) & 3)) << 3));
    }
#pragma unroll
    for (int i = 0; i < 4; ++i)
#pragma unroll
      for (int j = 0; j < 4; ++j)
        acc[i][j] = __builtin_amdgcn_mfma_f32_16x16x32_bf16(af[i], bfv[j], acc[i][j], 0, 0, 0);
  }

  float s1[4] = {0.f, 0.f, 0.f, 0.f};
  float s2[4] = {0.f, 0.f, 0.f, 0.f};
#pragma unroll
  for (int i = 0; i < 4; ++i) {
    int mbase = mt * 64 + i * 16 + lq * 4;
#pragma unroll
    for (int e = 0; e < 4; ++e) {
      int m = mbase + e;
      float bv = m < 512 ? b1[m] : b2[m - 512];
      float* yp = Y + ((size_t)bb * 1536 + m) * 2048 + nt * 128 + w * 64 + lm;
#pragma unroll
      for (int j = 0; j < 4; ++j) {
        float v = acc[i][j][e] + bv;
        yp[j * 16] = v;
        s1[i] += v; s2[i] += v * v;
      }
    }
  }
#pragma unroll
  for (int i = 0; i < 4; ++i) {
#pragma unroll
    for (int off = 32; off > 0; off >>= 1) {
      s1[i] += __shfl_xor(s1[i], off);
      s2[i] += __shfl_xor(s2[i], off);
    }
  }
  if (lane == 0) {
    if (mt < 8) {                                  // GN1: cpg=16, frag = 1 group
#pragma unroll
      for (int i = 0; i < 4; ++i) {
        int g = mt * 4 + i;
        atomicAdd(&raw1[(bb * 32 + g) * 2],     s1[i]);
        atomicAdd(&raw1[(bb * 32 + g) * 2 + 1], s2[i]);
      }
    } else {                                       // GN2: cpg=32, 2 frags = 1 group
#pragma unroll
      for (int i = 0; i < 2; ++i) {
        int g = (mt - 8) * 2 + i;
        atomicAdd(&raw2[(bb * 32 + g) * 2],     s1[2 * i] + s1[2 * i + 1]);
        atomicAdd(&raw2[(bb * 32 + g) * 2 + 1], s2[2 * i] + s2[2 * i + 1]);
      }
    }
  }
}

// ---------------------------------------------------------------------------
// 7b. GEMM3 split-K x2 (r2/r7-verified). M=512, N=2048, K=2048. 64x128 tile,
//     2 waves, grid.z = b*2+ks -> 1024 blocks. Conflict-free swizzle.
//     r5/r6 lesson: full-K fusion halves blocks but doubles each block's
//     serialized K-chain -> 2x slower. Split-K stays.
__global__ __launch_bounds__(128) void gemm3s_kernel(
    const u16* __restrict__ A, const u16* __restrict__ Bt,
    const float* __restrict__ bias, float* __restrict__ Yp)
{
  const int K = 2048;
  __shared__ short As[2][2048];
  __shared__ short Bs[2][4096];
  const int tid = threadIdx.x;
  const int lane = tid & 63;
  const int w = tid >> 6;
  const int nt = blockIdx.x, mt = blockIdx.y;
  const int bb = blockIdx.z >> 1, ks = blockIdx.z & 1;
  const u16* Ab = A + (size_t)mt * 64 * K + ks * 1024;
  const u16* Bb = Bt + ((size_t)bb * 2048 + (size_t)nt * 128) * K + ks * 1024;
  const int lm = lane & 15, lq = lane >> 4;
  f32x4 acc[4][4] = {};

  auto stage = [&](int buf, int kt) {
#pragma unroll
    for (int p = 0; p < 2; ++p) {
      int chunk = tid + 128 * p;
      int row = chunk >> 2;
      int ko = ((chunk & 3) ^ ((row >> 1) & 3)) << 3;
      gld16(Ab + (size_t)row * K + kt + ko, (char*)As[buf] + chunk * 16);
    }
#pragma unroll
    for (int p = 0; p < 4; ++p) {
      int chunk = tid + 128 * p;
      int row = chunk >> 2;
      int ko = ((chunk & 3) ^ ((row >> 1) & 3)) << 3;
      gld16(Bb + (size_t)row * K + kt + ko, (char*)Bs[buf] + chunk * 16);
    }
  };

  stage(0, 0);
  for (int s = 0; s < 32; ++s) {
    int cur = s & 1;
    __syncthreads();
    if (s + 1 < 32) stage(cur ^ 1, (s + 1) << 5);
    short8 af[4], bfv[4];
#pragma unroll
    for (int i = 0; i < 4; ++i) {
      int r = i * 16 + lm;
      af[i] = *(const short8*)(As[cur] + r * 32 + ((lq ^ ((r >> 1) & 3)) << 3));
    }
#pragma unroll
    for (int j = 0; j < 4; ++j) {
      int r = w * 64 + j * 16 + lm;
      bfv[j] = *(const short8*)(Bs[cur] + r * 32 + ((lq ^ ((r >> 1) & 3)) << 3));
    }
#pragma unroll
    for (int i = 0; i < 4; ++i)
#pragma unroll
      for (int j = 0; j < 4; ++j)
        acc[i][j] = __builtin_amdgcn_mfma_f32_16x16x32_bf16(af[i], bfv[j], acc[i][j], 0, 0, 0);
  }
#pragma unroll
  for (int i = 0; i < 4; ++i) {
    int mbase = mt * 64 + i * 16 + lq * 4;
#pragma unroll
    for (int e = 0; e < 4; ++e) {
      int m = mbase + e;
      float bv = ks ? 0.f : bias[m];
      float* yp = Yp + ((size_t)(ks * 4 + bb) * 512 + m) * 2048 + nt * 128 + w * 64 + lm;
#pragma unroll
      for (int j = 0; j < 4; ++j)
        yp[j * 16] = acc[i][j][e] + bv;
    }
  }
}

// ---------------------------------------------------------------------------
// 8b. stage-1 for split-K Y3: reads partial pair, float4-vectorized
__global__ void stats3p_kernel(const float* __restrict__ Yp, float* __restrict__ raw) {
  int chunk = blockIdx.x, g = blockIdx.y, b = blockIdx.z, tid = threadIdx.x;
  const f32x4* base = (const f32x4*)(Yp + ((size_t)b * 512 + g * 16) * 2048
                                        + (size_t)chunk * 4096);
  float s = 0.f, ss = 0.f;
#pragma unroll
  for (int i = 0; i < 4; ++i) {
    f32x4 a = base[tid + 256 * i];
    f32x4 c = base[tid + 256 * i + 1048576];    // +4194304 floats
#pragma unroll
    for (int e = 0; e < 4; ++e) {
      float v = a[e] + c[e];
      s += v; ss += v * v;
    }
  }
  __shared__ float s1[256], s2[256];
  s1[tid] = s; s2[tid] = ss;
  __syncthreads();
  for (int st = 128; st > 0; st >>= 1) {
    if (tid < st) { s1[tid] += s1[tid + st]; s2[tid] += s2[tid + st]; }
    __syncthreads();
  }
  if (tid == 0) {
    atomicAdd(&raw[(b * 32 + g) * 2],     s1[0]);
    atomicAdd(&raw[(b * 32 + g) * 2 + 1], s2[0]);
  }
}

// ---------------------------------------------------------------------------
// 9. normT1+normT2 merged (grid.y=24): y<8 -> GN1 rows (no featOut, X3T cols
//    1536+), y>=8 -> GN2 rows (featOut + X3T cols 512+). mu/rs inline from
//    raw sums (statsFin folded, r7-verified). Per-path code identical to the
//    two r7-verified normT launches.
__global__ void normT12_kernel(const float* __restrict__ Y,
                               const float* __restrict__ raw1,
                               const float* __restrict__ raw2,
                               const float* __restrict__ g1, const float* __restrict__ be1,
                               const float* __restrict__ g2, const float* __restrict__ be2,
                               u16* __restrict__ X3T, float* __restrict__ featOut) {
  __shared__ u16 tile[64][65];           // [t_local][c_local]
  int b = blockIdx.z, t0 = blockIdx.x * 64;
  int yb_idx = blockIdx.y;
  const int gn2 = yb_idx >= 8;
  int c0 = (gn2 ? yb_idx - 8 : yb_idx) * 64;
  const float* raw   = gn2 ? raw2 : raw1;
  const float* gamma = gn2 ? g2 : g1;
  const float* beta  = gn2 ? be2 : be1;
  const float inv_n  = gn2 ? (1.f / 65536.f) : (1.f / 32768.f);
  const int chBase   = gn2 ? 512 : 0;
  const int gShift   = gn2 ? 5 : 4;
  const int colBase  = gn2 ? 512 : 1536;
  const float* yb = Y + ((size_t)b * 1536 + chBase) * 2048;
  for (int i = threadIdx.x; i < 4096; i += 256) {
    int r = i >> 6, cc = i & 63;         // r: channel-local, cc: t-local
    int ch = c0 + r;
    int gI = (b * 32 + (ch >> gShift)) * 2;
    float mu = raw[gI] * inv_n;
    float var = raw[gI + 1] * inv_n - mu * mu;
    float rs = 1.0f / sqrtf(var + 1e-5f);
    float v = yb[(size_t)ch * 2048 + t0 + cc];
    float o = relu((v - mu) * rs * gamma[ch] + beta[ch]);
    tile[cc][r] = f2bf(o);
    if (gn2) featOut[((size_t)b * 1024 + ch) * 2048 + t0 + cc] = o;
  }
  __syncthreads();
  for (int i = threadIdx.x; i < 4096; i += 256) {
    int r = i >> 6, cc = i & 63;         // r: t-local, cc: c-local
    X3T[((size_t)b * 2048 + t0 + r) * 2048 + colBase + c0 + cc] = tile[r][cc];
  }
}

// ---------------------------------------------------------------------------
// 10. GN+ReLU for split-K Y3 partial pair -> fp32 mixed output.
//     float4-vectorized; statsFin folded (r7-verified).
__global__ void norm3_kernel(const float* __restrict__ Yp, const float* __restrict__ raw,
                             const float* __restrict__ gamma, const float* __restrict__ beta,
                             float* __restrict__ out) {
  int i4 = blockIdx.x * 256 + threadIdx.x;           // 1,048,576 float4s
  int b = i4 >> 18;                                  // 262144 f4 per batch
  int ch = (i4 >> 9) & 511;                          // 512 f4 per channel row
  int gI = (b * 32 + (ch >> 4)) * 2;
  float mu = raw[gI] * (1.f / 32768.f);
  float var = raw[gI + 1] * (1.f / 32768.f) - mu * mu;
  float rs = 1.0f / sqrtf(var + 1e-5f);
  float ga = gamma[ch], bt = beta[ch];
  f32x4 a = ((const f32x4*)Yp)[i4];
  f32x4 c = ((const f32x4*)Yp)[i4 + 1048576];
  f32x4 o;
#pragma unroll
  for (int e = 0; e < 4; ++e)
    o[e] = relu((a[e] + c[e] - mu) * rs * ga + bt);
  ((f32x4*)out)[i4] = o;
}

// ---------------------------------------------------------------------------
extern "C" void kernel_launch(void* const* d_in, const int* in_sizes, int n_in,
                              void* d_out, int out_size, void* d_ws, size_t ws_size,
                              hipStream_t stream) {
  const float* feature = (const float*)d_in[0];
  const float* frame   = (const float*)d_in[1];
  const float* W1 = (const float*)d_in[2];
  const float* b1 = (const float*)d_in[3];
  const float* g1 = (const float*)d_in[4];
  const float* be1 = (const float*)d_in[5];
  const float* W2 = (const float*)d_in[6];
  const float* b2 = (const float*)d_in[7];
  const float* g2 = (const float*)d_in[8];
  const float* be2 = (const float*)d_in[9];
  const float* W3 = (const float*)d_in[10];
  const float* b3 = (const float*)d_in[11];
  const float* g3 = (const float*)d_in[12];
  const float* be3 = (const float*)d_in[13];

  char* ws = (char*)d_ws;
  // Layout / stream-ordered aliasing (r2/r7-verified):
  //   X3T   [0, 32MiB)            bf16 (B,2048t,2048c)
  //   Y12f  [32MiB, 80MiB)        f32 (B,1536,2048) = GEMM1+2 output
  //   Y3p   [32MiB, 64MiB)        f32 split-K partial pair (after normT12)
  //   W3b   [64MiB, 66MiB)        bf16, written after normT12 (Y12 dead)
  //   partD [48MiB, +256KiB)      f64, dead before gemm12 writes Y12
  //   featT [80MiB, 88MiB)        bf16 (B,2048,512)
  //   W12b  [88MiB, +1.5MiB)      bf16 stacked W1;W2
  //   small tail after W12b (cdf/idx/raw1/raw2/raw3)
  u16*    X3T   = (u16*)(ws + 0);
  float*  Y12f  = (float*)(ws + 33554432);
  float*  Y3p   = (float*)(ws + 33554432);
  u16*    W3b   = (u16*)(ws + 67108864);
  double* partD = (double*)(ws + 50331648);
  u16*    featT = (u16*)(ws + 83886080);
  u16*    W12b  = (u16*)(ws + 92274688);
  int*    cdf   = (int*)(ws + 93847552);
  int*    idx   = (int*)(ws + 93863936);
  float*  raw1  = (float*)(ws + 93872128);
  float*  raw2  = (float*)(ws + 93873152);
  float*  raw3  = (float*)(ws + 93874176);

  float* outMixed = (float*)d_out;                       // (B,512,2048) fp32
  float* outFeat  = outMixed + (size_t)4 * 512 * 2048;   // (B,1024,2048) fp32

  colmean_part_kernel<<<dim3(16, 8), 256, 0, stream>>>(frame, partD, raw1);
  scanD_kernel<<<1, 256, 0, stream>>>(partD, cdf);
  argmin_kernel<<<2048, 256, 0, stream>>>(cdf, idx);
  gatherTrans_kernel<<<dim3(8, 32, 8), 256, 0, stream>>>(frame, feature, idx,
                                                         X3T, featT);
  convW12_kernel<<<768, 256, 0, stream>>>(W1, W2, W12b);
  gemm12_kernel<<<dim3(16, 24, 4), 128, 0, stream>>>(W12b, featT, b1, b2, Y12f,
                                                     raw1, raw2);
  normT12_kernel<<<dim3(32, 24, 4), 256, 0, stream>>>(Y12f, raw1, raw2,
                                                      g1, be1, g2, be2,
                                                      X3T, outFeat);
  convW_kernel<<<1024, 256, 0, stream>>>(W3, W3b);
  gemm3s_kernel<<<dim3(16, 8, 8), 128, 0, stream>>>(W3b, X3T, b3, Y3p);
  stats3p_kernel<<<dim3(8, 32, 4), 256, 0, stream>>>(Y3p, raw3);
  norm3_kernel<<<4096, 256, 0, stream>>>(Y3p, raw3, g3, be3, outMixed);
}